// Round 8
// baseline (7005.518 us; speedup 1.0000x reference)
//
#include <hip/hip_runtime.h>
#include <math.h>

// Problem constants
#define B_    512
#define T_    256
#define DIN   64
#define DS    64
#define KK    128   // DIN + DS
#define NN    2048
#define DOUT  10

// Tiling: 512 WGs = NTILES(4) x BTILES(128), 256 thr, 2 WG/CU.
#define NT      512
#define BT      4
#define NTILES  (NN / NT)      // 4
#define BTILES  (B_ / BT)      // 128
#define THREADS 256
#define NWG     (NTILES * BTILES)   // 512

// Workspace (float offsets): ps double-buffer | Et | counters
#define PS1      ((size_t)BTILES * NTILES * BT * DS)   // 131072 floats (512 KB)
#define PS_TOT   (2 * PS1)
#define ET_OFF   PS_TOT
#define ET_ELEMS ((size_t)KK * NN)                     // 262144 (1 MB)
#define BAR_OFF  (ET_OFF + ET_ELEMS)
#define BAR_UINTS 4096

__global__ __launch_bounds__(256) void pre_kernel(const float* __restrict__ enc,
                                                  float* __restrict__ ws,
                                                  float* __restrict__ out) {
    size_t i = (size_t)blockIdx.x * blockDim.x + threadIdx.x;
    size_t stride = (size_t)gridDim.x * blockDim.x;
    unsigned int* bar = (unsigned int*)(ws + BAR_OFF);
    for (size_t x = i; x < BAR_UINTS; x += stride) bar[x] = 0u;
    for (size_t x = i; x < ET_ELEMS; x += stride) {    // Et[k][n] = enc[n][k]
        int k = (int)(x >> 11);
        int n = (int)(x & 2047);
        ws[ET_OFF + x] = enc[(size_t)n * KK + k];
    }
    for (size_t x = i; x < (size_t)B_ * DOUT; x += stride) out[x] = 0.0f;
}

// R7 protocol (proven): fence-free, coalesced sc1 exchange, monotonic
// per-column counters, double-buffered ps, encode split around the poll.
// R8 changes: b128 Et/sd loads (each weight element read once per WG),
// bank-rotated decode, butterfly reduces, seq prefetch.
__global__ __launch_bounds__(THREADS, 2) void persist_kernel(
    const float* __restrict__ seq,   // [B][T][DIN]
    const float* __restrict__ Et,    // [KK][NN]
    const float* __restrict__ bias,
    const float* __restrict__ gain,
    const float* __restrict__ sd,    // [NN][DS]
    const float* __restrict__ dec,   // [NN][DOUT]
    float* __restrict__ ps,          // [2][BTILES][NTILES][BT][DS]
    unsigned int* __restrict__ bar,  // cnt[BTILES * 32]
    float* __restrict__ out)
{
    __shared__ float xs[BT][132];    // x_aug tile
    __shared__ float As[BT][516];    // activations [row][neuron], pad 516
    __shared__ float Dp[4][BT][68];  // decode cross-wave partials

    const int tid = threadIdx.x;
    const int nt = blockIdx.x & (NTILES - 1);
    const int bt = blockIdx.x >> 2;
    const int n0 = nt * NT;
    const int b0 = bt * BT;

    unsigned int* cnt = bar + (size_t)bt * 32;

    const int w  = tid >> 6;           // wave 0..3
    const int l  = tid & 63;
    const int kh = l >> 5;             // k half-of-wave (shfl_xor(32) partner)
    const int gq = w * 32 + (l & 31);  // neuron-quad 0..127
    const int nq = 4 * gq;             // local neuron base
    const int rs = tid >> 6;           // fan-in row
    const int cs = tid & 63;           // fan-in col
    const int jg = (tid & 15) << 2;    // decode col group
    const int nr = tid >> 4;           // decode n-range 0..15 (w*4 + l>>4)

    // loop-invariant per-neuron params (4 neurons/lane)
    const float4 gg4 = *(const float4*)&gain[n0 + nq];
    const float4 bb4 = *(const float4*)&bias[n0 + nq];

    // seq prefetch register: u value for (row w, col l) at step t
    float u_reg = seq[((size_t)(b0 + w) * T_ + 0) * DIN + l];

#define ENC_STEP(kb)                                                        \
    do {                                                                    \
        const float* ep = &Et[(size_t)(kb) * NN + n0 + nq];                 \
        const float4 e0 = *(const float4*)(ep);                             \
        const float4 e1 = *(const float4*)(ep + NN);                        \
        const float4 e2 = *(const float4*)(ep + 2 * (size_t)NN);            \
        const float4 e3 = *(const float4*)(ep + 3 * (size_t)NN);            \
        const float4 x0 = *(const float4*)&xs[0][kb];                       \
        const float4 x1 = *(const float4*)&xs[1][kb];                       \
        const float4 x2 = *(const float4*)&xs[2][kb];                       \
        const float4 x3 = *(const float4*)&xs[3][kb];                       \
        acc0.x += e0.x*x0.x + e1.x*x0.y + e2.x*x0.z + e3.x*x0.w;            \
        acc0.y += e0.y*x0.x + e1.y*x0.y + e2.y*x0.z + e3.y*x0.w;            \
        acc0.z += e0.z*x0.x + e1.z*x0.y + e2.z*x0.z + e3.z*x0.w;            \
        acc0.w += e0.w*x0.x + e1.w*x0.y + e2.w*x0.z + e3.w*x0.w;            \
        acc1.x += e0.x*x1.x + e1.x*x1.y + e2.x*x1.z + e3.x*x1.w;            \
        acc1.y += e0.y*x1.x + e1.y*x1.y + e2.y*x1.z + e3.y*x1.w;            \
        acc1.z += e0.z*x1.x + e1.z*x1.y + e2.z*x1.z + e3.z*x1.w;            \
        acc1.w += e0.w*x1.x + e1.w*x1.y + e2.w*x1.z + e3.w*x1.w;            \
        acc2.x += e0.x*x2.x + e1.x*x2.y + e2.x*x2.z + e3.x*x2.w;            \
        acc2.y += e0.y*x2.x + e1.y*x2.y + e2.y*x2.z + e3.y*x2.w;            \
        acc2.z += e0.z*x2.x + e1.z*x2.y + e2.z*x2.z + e3.z*x2.w;            \
        acc2.w += e0.w*x2.x + e1.w*x2.y + e2.w*x2.z + e3.w*x2.w;            \
        acc3.x += e0.x*x3.x + e1.x*x3.y + e2.x*x3.z + e3.x*x3.w;            \
        acc3.y += e0.y*x3.x + e1.y*x3.y + e2.y*x3.z + e3.y*x3.w;            \
        acc3.z += e0.z*x3.x + e1.z*x3.y + e2.z*x3.z + e3.z*x3.w;            \
        acc3.w += e0.w*x3.x + e1.w*x3.y + e2.w*x3.z + e3.w*x3.w;            \
    } while (0)

    for (int t = 0; t < T_; ++t) {
        // ---- stage u_t (from prefetch register) ----
        xs[w][l] = u_reg;
        __syncthreads();
        // prefetch next step's u
        {
            const int tn = (t + 1 < T_) ? t + 1 : t;
            u_reg = seq[((size_t)(b0 + w) * T_ + tn) * DIN + l];
        }

        // ---- encode PASS A: k in [kh*32, kh*32+32)  (input half, pre-poll) ----
        float4 acc0 = {0,0,0,0}, acc1 = {0,0,0,0}, acc2 = {0,0,0,0}, acc3 = {0,0,0,0};
        {
            const int ka = kh * 32;
            #pragma unroll
            for (int i = 0; i < 8; ++i) ENC_STEP(ka + 4 * i);
        }

        // ---- acquire state s(t-1): poll + coalesced sc1 fan-in ----
        if (t > 0) {
            if (tid == 0) {
                while (__hip_atomic_load(cnt, __ATOMIC_RELAXED, __HIP_MEMORY_SCOPE_AGENT)
                       < 4u * (unsigned)t)
                    __builtin_amdgcn_s_sleep(1);
            }
            __syncthreads();
            const float* pb = ps + (size_t)((t - 1) & 1) * PS1;
            float ssum = 0.f;
            #pragma unroll
            for (int p = 0; p < NTILES; ++p)
                ssum += __hip_atomic_load(
                    pb + (((size_t)bt * NTILES + p) * BT + rs) * DS + cs,
                    __ATOMIC_RELAXED, __HIP_MEMORY_SCOPE_AGENT);
            xs[rs][DIN + cs] = ssum;
        } else {
            xs[rs][DIN + cs] = 0.f;
        }
        __syncthreads();

        // ---- encode PASS B: k in [64+kh*32, 64+kh*32+32)  (state half) ----
        {
            const int kb0 = 64 + kh * 32;
            #pragma unroll
            for (int i = 0; i < 8; ++i) ENC_STEP(kb0 + 4 * i);
        }

        // reduce the two k-halves (butterfly across lane^32)
        acc0.x += __shfl_xor(acc0.x, 32); acc0.y += __shfl_xor(acc0.y, 32);
        acc0.z += __shfl_xor(acc0.z, 32); acc0.w += __shfl_xor(acc0.w, 32);
        acc1.x += __shfl_xor(acc1.x, 32); acc1.y += __shfl_xor(acc1.y, 32);
        acc1.z += __shfl_xor(acc1.z, 32); acc1.w += __shfl_xor(acc1.w, 32);
        acc2.x += __shfl_xor(acc2.x, 32); acc2.y += __shfl_xor(acc2.y, 32);
        acc2.z += __shfl_xor(acc2.z, 32); acc2.w += __shfl_xor(acc2.w, 32);
        acc3.x += __shfl_xor(acc3.x, 32); acc3.y += __shfl_xor(acc3.y, 32);
        acc3.z += __shfl_xor(acc3.z, 32); acc3.w += __shfl_xor(acc3.w, 32);

        // ---- activation -> As (kh==0 lanes write the quad, b128) ----
        if (kh == 0) {
            float4 v;
            v.x = fabsf(gg4.x*acc0.x + bb4.x); v.y = fabsf(gg4.y*acc0.y + bb4.y);
            v.z = fabsf(gg4.z*acc0.z + bb4.z); v.w = fabsf(gg4.w*acc0.w + bb4.w);
            *(float4*)&As[0][nq] = v;
            v.x = fabsf(gg4.x*acc1.x + bb4.x); v.y = fabsf(gg4.y*acc1.y + bb4.y);
            v.z = fabsf(gg4.z*acc1.z + bb4.z); v.w = fabsf(gg4.w*acc1.w + bb4.w);
            *(float4*)&As[1][nq] = v;
            v.x = fabsf(gg4.x*acc2.x + bb4.x); v.y = fabsf(gg4.y*acc2.y + bb4.y);
            v.z = fabsf(gg4.z*acc2.z + bb4.z); v.w = fabsf(gg4.w*acc2.w + bb4.w);
            *(float4*)&As[2][nq] = v;
            v.x = fabsf(gg4.x*acc3.x + bb4.x); v.y = fabsf(gg4.y*acc3.y + bb4.y);
            v.z = fabsf(gg4.z*acc3.z + bb4.z); v.w = fabsf(gg4.w*acc3.w + bb4.w);
            *(float4*)&As[3][nq] = v;
        }
        __syncthreads();

        if (t == T_ - 1) {
            // ---- final projection: out += A_tile @ dec_tile ----
            for (int idx = tid; idx < BT * DOUT; idx += THREADS) {
                const int r = idx / DOUT;
                const int d = idx % DOUT;
                float o = 0.f;
                #pragma unroll 8
                for (int n = 0; n < NT; ++n)
                    o += As[r][n] * dec[(size_t)(n0 + n) * DOUT + d];
                atomicAdd(&out[(size_t)(b0 + r) * DOUT + d], o);
            }
            return;
        }

        // ---- decode: thread = 4 cols (jg) x n-range (nr, 32 neurons) ----
        {
            float4 d0 = {0,0,0,0}, d1 = {0,0,0,0}, d2 = {0,0,0,0}, d3 = {0,0,0,0};
            #pragma unroll
            for (int i = 0; i < 8; ++i) {
                const int nn = nr * 32 + (((i + nr) & 7) << 2);   // bank-rotated
                const float* sp = &sd[(size_t)(n0 + nn) * DS + jg];
                const float4 s0 = *(const float4*)(sp);
                const float4 s1 = *(const float4*)(sp + DS);
                const float4 s2 = *(const float4*)(sp + 2 * DS);
                const float4 s3 = *(const float4*)(sp + 3 * DS);
                const float4 a0 = *(const float4*)&As[0][nn];
                const float4 a1 = *(const float4*)&As[1][nn];
                const float4 a2 = *(const float4*)&As[2][nn];
                const float4 a3 = *(const float4*)&As[3][nn];
                d0.x += a0.x*s0.x + a0.y*s1.x + a0.z*s2.x + a0.w*s3.x;
                d0.y += a0.x*s0.y + a0.y*s1.y + a0.z*s2.y + a0.w*s3.y;
                d0.z += a0.x*s0.z + a0.y*s1.z + a0.z*s2.z + a0.w*s3.z;
                d0.w += a0.x*s0.w + a0.y*s1.w + a0.z*s2.w + a0.w*s3.w;
                d1.x += a1.x*s0.x + a1.y*s1.x + a1.z*s2.x + a1.w*s3.x;
                d1.y += a1.x*s0.y + a1.y*s1.y + a1.z*s2.y + a1.w*s3.y;
                d1.z += a1.x*s0.z + a1.y*s1.z + a1.z*s2.z + a1.w*s3.z;
                d1.w += a1.x*s0.w + a1.y*s1.w + a1.z*s2.w + a1.w*s3.w;
                d2.x += a2.x*s0.x + a2.y*s1.x + a2.z*s2.x + a2.w*s3.x;
                d2.y += a2.x*s0.y + a2.y*s1.y + a2.z*s2.y + a2.w*s3.y;
                d2.z += a2.x*s0.z + a2.y*s1.z + a2.z*s2.z + a2.w*s3.z;
                d2.w += a2.x*s0.w + a2.y*s1.w + a2.z*s2.w + a2.w*s3.w;
                d3.x += a3.x*s0.x + a3.y*s1.x + a3.z*s2.x + a3.w*s3.x;
                d3.y += a3.x*s0.y + a3.y*s1.y + a3.z*s2.y + a3.w*s3.y;
                d3.z += a3.x*s0.z + a3.y*s1.z + a3.z*s2.z + a3.w*s3.z;
                d3.w += a3.x*s0.w + a3.y*s1.w + a3.z*s2.w + a3.w*s3.w;
            }
            // butterfly over the wave's 4 n-ranges (lane^16, lane^32)
            #pragma unroll
            for (int st = 16; st <= 32; st <<= 1) {
                d0.x += __shfl_xor(d0.x, st); d0.y += __shfl_xor(d0.y, st);
                d0.z += __shfl_xor(d0.z, st); d0.w += __shfl_xor(d0.w, st);
                d1.x += __shfl_xor(d1.x, st); d1.y += __shfl_xor(d1.y, st);
                d1.z += __shfl_xor(d1.z, st); d1.w += __shfl_xor(d1.w, st);
                d2.x += __shfl_xor(d2.x, st); d2.y += __shfl_xor(d2.y, st);
                d2.z += __shfl_xor(d2.z, st); d2.w += __shfl_xor(d2.w, st);
                d3.x += __shfl_xor(d3.x, st); d3.y += __shfl_xor(d3.y, st);
                d3.z += __shfl_xor(d3.z, st); d3.w += __shfl_xor(d3.w, st);
            }
            if (w > 0 && l < 16) {
                *(float4*)&Dp[w][0][jg] = d0;
                *(float4*)&Dp[w][1][jg] = d1;
                *(float4*)&Dp[w][2][jg] = d2;
                *(float4*)&Dp[w][3][jg] = d3;
            }
            __syncthreads();
            if (w == 0 && l < 16) {
                #pragma unroll
                for (int p = 1; p < 4; ++p) {
                    const float4 q0 = *(const float4*)&Dp[p][0][jg];
                    const float4 q1 = *(const float4*)&Dp[p][1][jg];
                    const float4 q2 = *(const float4*)&Dp[p][2][jg];
                    const float4 q3 = *(const float4*)&Dp[p][3][jg];
                    d0.x += q0.x; d0.y += q0.y; d0.z += q0.z; d0.w += q0.w;
                    d1.x += q1.x; d1.y += q1.y; d1.z += q1.z; d1.w += q1.w;
                    d2.x += q2.x; d2.y += q2.y; d2.z += q2.z; d2.w += q2.w;
                    d3.x += q3.x; d3.y += q3.y; d3.z += q3.z; d3.w += q3.w;
                }
                // sc1 store partial: ps[t&1][bt][nt][r][jg..jg+3] as 2x u64
                float* pw = ps + (size_t)(t & 1) * PS1
                               + (((size_t)bt * NTILES + nt) * BT) * DS + jg;
                float2 h;
                h.x = d0.x; h.y = d0.y;
                __hip_atomic_store((unsigned long long*)(pw + 0*DS),     *(unsigned long long*)&h, __ATOMIC_RELAXED, __HIP_MEMORY_SCOPE_AGENT);
                h.x = d0.z; h.y = d0.w;
                __hip_atomic_store((unsigned long long*)(pw + 0*DS + 2), *(unsigned long long*)&h, __ATOMIC_RELAXED, __HIP_MEMORY_SCOPE_AGENT);
                h.x = d1.x; h.y = d1.y;
                __hip_atomic_store((unsigned long long*)(pw + 1*DS),     *(unsigned long long*)&h, __ATOMIC_RELAXED, __HIP_MEMORY_SCOPE_AGENT);
                h.x = d1.z; h.y = d1.w;
                __hip_atomic_store((unsigned long long*)(pw + 1*DS + 2), *(unsigned long long*)&h, __ATOMIC_RELAXED, __HIP_MEMORY_SCOPE_AGENT);
                h.x = d2.x; h.y = d2.y;
                __hip_atomic_store((unsigned long long*)(pw + 2*DS),     *(unsigned long long*)&h, __ATOMIC_RELAXED, __HIP_MEMORY_SCOPE_AGENT);
                h.x = d2.z; h.y = d2.w;
                __hip_atomic_store((unsigned long long*)(pw + 2*DS + 2), *(unsigned long long*)&h, __ATOMIC_RELAXED, __HIP_MEMORY_SCOPE_AGENT);
                h.x = d3.x; h.y = d3.y;
                __hip_atomic_store((unsigned long long*)(pw + 3*DS),     *(unsigned long long*)&h, __ATOMIC_RELAXED, __HIP_MEMORY_SCOPE_AGENT);
                h.x = d3.z; h.y = d3.w;
                __hip_atomic_store((unsigned long long*)(pw + 3*DS + 2), *(unsigned long long*)&h, __ATOMIC_RELAXED, __HIP_MEMORY_SCOPE_AGENT);
            }
        }

        // ---- arrive: drain sc1 stores (wave 0 holds them; tid0 is wave 0) ----
        asm volatile("s_waitcnt vmcnt(0)" ::: "memory");
        __syncthreads();
        if (tid == 0)
            __hip_atomic_fetch_add(cnt, 1u, __ATOMIC_RELAXED, __HIP_MEMORY_SCOPE_AGENT);
    }
#undef ENC_STEP
}

extern "C" void kernel_launch(void* const* d_in, const int* in_sizes, int n_in,
                              void* d_out, int out_size, void* d_ws, size_t ws_size,
                              hipStream_t stream) {
    const float* seq  = (const float*)d_in[0];
    const float* enc  = (const float*)d_in[1];
    const float* bias = (const float*)d_in[2];
    const float* gain = (const float*)d_in[3];
    const float* sd   = (const float*)d_in[4];
    const float* dec  = (const float*)d_in[5];
    float* out = (float*)d_out;
    float* ws  = (float*)d_ws;   // ps[2] | Et | counters  (~2.1 MB)

    pre_kernel<<<dim3(1024), dim3(256), 0, stream>>>(enc, ws, out);

    float* ps = ws;
    const float* Et = ws + ET_OFF;
    unsigned int* bar = (unsigned int*)(ws + BAR_OFF);

    persist_kernel<<<dim3(NWG), dim3(THREADS), 0, stream>>>(
        seq, Et, bias, gain, sd, dec, ps, bar, out);
}